// Round 1
// baseline (4179.076 us; speedup 1.0000x reference)
//
#include <hip/hip_runtime.h>
#include <hip/hip_bf16.h>
#include <stdint.h>
#include <stddef.h>

using bf16 = __hip_bfloat16;
typedef __attribute__((ext_vector_type(8))) short short8;
typedef __attribute__((ext_vector_type(4))) float f32x4;

constexpr int BATCH = 2048;
constexpr int NN    = 1024;
constexpr int H1C   = 3072;
constexpr int H2C   = 4096;
constexpr int CAP   = 128;   // max nnz per sparse row (Binom(4096,0.01): mean 41, P(>128) ~ 1e-12)

// CSR global row offsets
constexpr int ROW_WV1 = 0;                 // 5*3072 rows, len 3072
constexpr int ROW_WO1 = 5 * H1C;           // 15360: 5*1024 rows, len 3072
constexpr int ROW_WV2 = ROW_WO1 + 5 * NN;  // 20480: 5*4096 rows, len 4096
constexpr int ROW_WO2 = ROW_WV2 + 5 * H2C; // 40960: 5*1024 rows, len 4096
constexpr int ROWS_TOTAL = ROW_WO2 + 5 * NN; // 46080

__device__ __forceinline__ void gload16(const void* g, void* lds_base) {
  __builtin_amdgcn_global_load_lds(
      (const __attribute__((address_space(1))) void*)g,
      (__attribute__((address_space(3))) void*)lds_base, 16, 0, 0);
}

// ---- bf16 MFMA GEMM (m97-structure): C[M,Nd] = A[M,K] @ BT[Nd,K]^T (+add), f32 (+bf16) out
// 128x128 tile, BK=32, 4 waves (each 64x64), global_load_lds staging.
__global__ __launch_bounds__(256, 2) void gemm_bt(
    const bf16* __restrict__ A, const bf16* __restrict__ BT,
    float* __restrict__ C, bf16* __restrict__ Cb, const float* __restrict__ add,
    int M, int Nd, int K)
{
  __shared__ bf16 As[128 * 32];
  __shared__ bf16 Bs[128 * 32];
  const int tid  = threadIdx.x;
  const int lane = tid & 63;
  const int w    = tid >> 6;
  const int bn = blockIdx.x, bm = blockIdx.y;
  const int wm = (w >> 1) * 64, wn = (w & 1) * 64;
  const int l15 = lane & 15;
  const int lk  = (lane >> 4) * 8;   // k elem offset of A/B fragment
  const int ld4 = (lane >> 4) * 4;   // row offset of D fragment
  const int sr  = lane >> 2;         // staging: row within 16-row slot
  const int kc  = (lane & 3) * 8;    // staging: k elem offset

  f32x4 acc[4][4];
#pragma unroll
  for (int i = 0; i < 4; ++i)
#pragma unroll
    for (int j = 0; j < 4; ++j)
#pragma unroll
      for (int e = 0; e < 4; ++e) acc[i][j][e] = 0.f;

  const size_t rA = (size_t)bm * 128;
  const size_t rB = (size_t)bn * 128;

  for (int kt = 0; kt < K; kt += 32) {
#pragma unroll
    for (int c = 0; c < 2; ++c) {
      const int slot = w * 2 + c;             // 8 slots of 16 rows x 32 k (1 KiB)
      const int r = slot * 16 + sr;
      gload16(A  + (rA + r) * (size_t)K + kt + kc, &As[slot * 512]);
      gload16(BT + (rB + r) * (size_t)K + kt + kc, &Bs[slot * 512]);
    }
    __syncthreads();
    short8 af[4], bfr[4];
#pragma unroll
    for (int f = 0; f < 4; ++f) {
      af[f]  = *(const short8*)&As[(wm + f * 16 + l15) * 32 + lk];
      bfr[f] = *(const short8*)&Bs[(wn + f * 16 + l15) * 32 + lk];
    }
#pragma unroll
    for (int i = 0; i < 4; ++i)
#pragma unroll
      for (int j = 0; j < 4; ++j)
        acc[i][j] = __builtin_amdgcn_mfma_f32_16x16x32_bf16(af[i], bfr[j], acc[i][j], 0, 0, 0);
    __syncthreads();
  }

#pragma unroll
  for (int i = 0; i < 4; ++i) {
    const int row0 = bm * 128 + wm + i * 16 + ld4;
#pragma unroll
    for (int j = 0; j < 4; ++j) {
      const int col = bn * 128 + wn + j * 16 + l15;
#pragma unroll
      for (int e = 0; e < 4; ++e) {
        const size_t o = (size_t)(row0 + e) * Nd + col;
        float v = acc[i][j][e];
        if (add) v += add[o];
        C[o] = v;
        if (Cb) Cb[o] = __float2bfloat16(v);
      }
    }
  }
}

// ---- prep: SmIT[k][n][m] = bf16(S[k][m][n] - (m==n))
__global__ __launch_bounds__(256) void prep_smit(const float* __restrict__ S, bf16* __restrict__ out)
{
  __shared__ float ls[64][65];
  const int k = blockIdx.z;
  const int n0 = blockIdx.x * 64, m0 = blockIdx.y * 64;
  const float* Sk = S + (size_t)k * NN * NN;
  bf16* ok = out + (size_t)k * NN * NN;
  const int tc = threadIdx.x & 63, tr = threadIdx.x >> 6;
#pragma unroll
  for (int i = 0; i < 16; ++i) {
    const int r = tr + i * 4;
    ls[r][tc] = Sk[(size_t)(m0 + r) * NN + n0 + tc];
  }
  __syncthreads();
#pragma unroll
  for (int i = 0; i < 16; ++i) {
    const int r = tr + i * 4; // out row n = n0+r, col m = m0+tc
    float v = ls[tc][r] - ((m0 + tc) == (n0 + r) ? 1.f : 0.f);
    ok[(size_t)(n0 + r) * NN + m0 + tc] = __float2bfloat16(v);
  }
}

// ---- prep: out[h][n] = bf16(Bsrc[n][h]);  Bsrc is (NN, H)
__global__ __launch_bounds__(256) void prep_bt(const float* __restrict__ Bsrc, bf16* __restrict__ out, int H)
{
  __shared__ float ls[64][65];
  const int h0 = blockIdx.x * 64, n0 = blockIdx.y * 64;
  const int tc = threadIdx.x & 63, tr = threadIdx.x >> 6;
#pragma unroll
  for (int i = 0; i < 16; ++i) {
    const int r = tr + i * 4;
    ls[r][tc] = Bsrc[(size_t)(n0 + r) * H + h0 + tc];
  }
  __syncthreads();
#pragma unroll
  for (int i = 0; i < 16; ++i) {
    const int r = tr + i * 4; // out row h = h0+r, col n = n0+tc
    out[(size_t)(h0 + r) * NN + n0 + tc] = __float2bfloat16(ls[tc][r]);
  }
}

// ---- CSR build: one block per row, ordered compaction (deterministic)
__global__ __launch_bounds__(256) void csr_build(
    const float* __restrict__ W, int rowlen,
    float* __restrict__ vals, int* __restrict__ cols, int* __restrict__ nnz, int row_off)
{
  const int row = blockIdx.x;
  const float* wr = W + (size_t)row * rowlen;
  const size_t base = (size_t)(row_off + row) * CAP;
  __shared__ int wtot[4];
  __shared__ int cbase;
  if (threadIdx.x == 0) cbase = 0;
  __syncthreads();
  const int lane = threadIdx.x & 63, wv = threadIdx.x >> 6;
  for (int c0 = 0; c0 < rowlen; c0 += 256) {
    const int c = c0 + threadIdx.x;
    const float v = wr[c];
    const bool nz = (v != 0.f);
    const unsigned long long m = __ballot(nz);
    const int rank = __popcll(m & ((1ull << lane) - 1ull));
    if (lane == 0) wtot[wv] = __popcll(m);
    __syncthreads();
    int pre = cbase;
    for (int i = 0; i < wv; ++i) pre += wtot[i];
    if (nz) {
      const int p = pre + rank;
      if (p < CAP) { vals[base + p] = v; cols[base + p] = c; }
    }
    __syncthreads();
    if (threadIdx.x == 0) cbase += wtot[0] + wtot[1] + wtot[2] + wtot[3];
    __syncthreads();
  }
  if (threadIdx.x == 0) nnz[row_off + row] = (cbase < CAP ? cbase : CAP);
}

// ---- cn_update + clip + 2*atanh:  out[h,b] = log((1+u)/(1-u)), u = clipped prod of nz gathers
__global__ __launch_bounds__(256) void cn_kernel(
    const float* __restrict__ src,   // (rows, BATCH)
    const int* __restrict__ idx, int D,
    float* __restrict__ out)         // (H, BATCH)
{
  const int b = blockIdx.y * 256 + threadIdx.x;
  const int h = blockIdx.x;
  const int* ir = idx + (size_t)h * D;
  float prod = 1.f;
  bool any = false;
  for (int d = 0; d < D; ++d) {
    const float v = src[(size_t)ir[d] * BATCH + b];
    const bool nz = (v != 0.f);
    any |= nz;
    prod *= nz ? v : 1.f;
  }
  float u = any ? prod : 0.f;
  u = fminf(fmaxf(u, -0.999999f), 0.999999f);
  out[(size_t)h * BATCH + b] = logf((1.f + u) / (1.f - u));
}

// ---- sparse Wv apply + tanh (in-place on z): z[h,b] = tanh(0.5*(z[h,b] + sum val*t1[col,b]))
__global__ __launch_bounds__(256) void sparse_wv(
    float* __restrict__ zio, const float* __restrict__ t1,
    const float* __restrict__ vals, const int* __restrict__ cols, const int* __restrict__ nnz,
    int rowoff)
{
  const int b = blockIdx.y * 256 + threadIdx.x;
  const int h = blockIdx.x;
  const int rg = rowoff + h;
  const float* vr = vals + (size_t)rg * CAP;
  const int*   cr = cols + (size_t)rg * CAP;
  const int n = nnz[rg];
  float acc = zio[(size_t)h * BATCH + b];
  for (int j = 0; j < n; ++j)
    acc += vr[j] * t1[(size_t)cr[j] * BATCH + b];
  zio[(size_t)h * BATCH + b] = tanhf(0.5f * acc);
}

// ---- sparse Wout apply: xp[n,b] = sum val*t3[col,b]
__global__ __launch_bounds__(256) void sparse_wo(
    const float* __restrict__ t3,
    const float* __restrict__ vals, const int* __restrict__ cols, const int* __restrict__ nnz,
    int rowoff, float* __restrict__ xp)
{
  const int b = blockIdx.y * 256 + threadIdx.x;
  const int n = blockIdx.x;
  const int rg = rowoff + n;
  const float* vr = vals + (size_t)rg * CAP;
  const int*   cr = cols + (size_t)rg * CAP;
  const int cnt = nnz[rg];
  float acc = 0.f;
  for (int j = 0; j < cnt; ++j)
    acc += vr[j] * t3[(size_t)cr[j] * BATCH + b];
  xp[(size_t)n * BATCH + b] = acc;
}

// ---- fused epilogue: x_new = chS + xp^T; write sigmoid->out, x f32, x bf16 (B,N) and tanh(0.5x)->tfT (N,B)
__global__ __launch_bounds__(256) void fuse_out(
    const float* __restrict__ xpT,  // (NN, BATCH)
    const float* __restrict__ chS,  // (BATCH, NN)
    float* __restrict__ dout,       // (BATCH, NN)
    float* __restrict__ xf,         // (BATCH, NN)
    bf16* __restrict__ xb,          // (BATCH, NN)
    float* __restrict__ tfT)        // (NN, BATCH)
{
  __shared__ float lc[64][65];  // chS tile [b][n]
  __shared__ float lx[64][65];  // xpT tile [n][b]
  const int n0 = blockIdx.x * 64, b0 = blockIdx.y * 64;
  const int tc = threadIdx.x & 63, tr = threadIdx.x >> 6;
#pragma unroll
  for (int i = 0; i < 16; ++i) {
    const int r = tr + i * 4;
    lc[r][tc] = chS[(size_t)(b0 + r) * NN + n0 + tc];
    lx[r][tc] = xpT[(size_t)(n0 + r) * BATCH + b0 + tc];
  }
  __syncthreads();
#pragma unroll
  for (int i = 0; i < 16; ++i) {      // (B,N) orientation: r=local b, tc=local n
    const int r = tr + i * 4;
    const float v = lc[r][tc] + lx[tc][r];
    const size_t o = (size_t)(b0 + r) * NN + n0 + tc;
    dout[o] = 1.f / (1.f + expf(-v));
    xf[o] = v;
    xb[o] = __float2bfloat16(v);
  }
#pragma unroll
  for (int i = 0; i < 16; ++i) {      // (N,B) orientation: r=local n, tc=local b
    const int r = tr + i * 4;
    const float v = lc[tc][r] + lx[r][tc];
    tfT[(size_t)(n0 + r) * BATCH + b0 + tc] = tanhf(0.5f * v);
  }
}

// ---- initial prep (k=0): from x (B,N) make xb (B,N) and tfT (N,B)
__global__ __launch_bounds__(256) void init_prep(
    const float* __restrict__ x, bf16* __restrict__ xb, float* __restrict__ tfT)
{
  __shared__ float ls[64][65];
  const int n0 = blockIdx.x * 64, b0 = blockIdx.y * 64;
  const int tc = threadIdx.x & 63, tr = threadIdx.x >> 6;
#pragma unroll
  for (int i = 0; i < 16; ++i) {
    const int r = tr + i * 4;
    const size_t o = (size_t)(b0 + r) * NN + n0 + tc;
    const float v = x[o];
    ls[r][tc] = v;
    xb[o] = __float2bfloat16(v);
  }
  __syncthreads();
#pragma unroll
  for (int i = 0; i < 16; ++i) {
    const int r = tr + i * 4; // r = local n, tc = local b
    tfT[(size_t)(n0 + r) * BATCH + b0 + tc] = tanhf(0.5f * ls[tc][r]);
  }
}

extern "C" void kernel_launch(void* const* d_in, const int* in_sizes, int n_in,
                              void* d_out, int out_size, void* d_ws, size_t ws_size,
                              hipStream_t stream)
{
  const float* x_in  = (const float*)d_in[0];
  const float* S     = (const float*)d_in[1];
  const float* B1    = (const float*)d_in[2];
  const float* B2    = (const float*)d_in[3];
  const float* Wv1   = (const float*)d_in[4];
  const float* Wout1 = (const float*)d_in[5];
  const float* Wv2   = (const float*)d_in[6];
  const float* Wout2 = (const float*)d_in[7];
  const int* idx1f   = (const int*)d_in[8];
  const int* idx1m   = (const int*)d_in[9];
  const int* idx2f   = (const int*)d_in[10];
  const int* idx2m   = (const int*)d_in[11];
  float* out = (float*)d_out;

  uint8_t* p = (uint8_t*)d_ws;
  auto alloc = [&](size_t bytes) -> void* {
    void* r = p;
    p += (bytes + 255) & ~(size_t)255;
    return r;
  };
  bf16*  SmIT = (bf16*)alloc((size_t)10 * NN * NN * sizeof(bf16));
  bf16*  B1T  = (bf16*)alloc((size_t)H1C * NN * sizeof(bf16));
  bf16*  B2T  = (bf16*)alloc((size_t)H2C * NN * sizeof(bf16));
  float* cvals = (float*)alloc((size_t)ROWS_TOTAL * CAP * sizeof(float));
  int*   ccols = (int*)alloc((size_t)ROWS_TOTAL * CAP * sizeof(int));
  int*   cnnz  = (int*)alloc((size_t)ROWS_TOTAL * sizeof(int));
  float* xf   = (float*)alloc((size_t)BATCH * NN * sizeof(float));
  bf16*  xb   = (bf16*)alloc((size_t)BATCH * NN * sizeof(bf16));
  float* tfT  = (float*)alloc((size_t)NN * BATCH * sizeof(float));
  float* chS  = (float*)alloc((size_t)BATCH * NN * sizeof(float));
  bf16*  chSb = (bf16*)alloc((size_t)BATCH * NN * sizeof(bf16));
  float* t1T  = (float*)alloc((size_t)H2C * BATCH * sizeof(float)); // also t3T
  float* zT   = (float*)alloc((size_t)H2C * BATCH * sizeof(float)); // also t2T (in-place)
  float* xpT  = (float*)alloc((size_t)NN * BATCH * sizeof(float));
  (void)ws_size; (void)in_sizes; (void)n_in; (void)out_size;

  // --- per-call prep
  prep_smit<<<dim3(NN / 64, NN / 64, 10), 256, 0, stream>>>(S, SmIT);
  prep_bt<<<dim3(H1C / 64, NN / 64), 256, 0, stream>>>(B1, B1T, H1C);
  prep_bt<<<dim3(H2C / 64, NN / 64), 256, 0, stream>>>(B2, B2T, H2C);
  csr_build<<<5 * H1C, 256, 0, stream>>>(Wv1,   H1C, cvals, ccols, cnnz, ROW_WV1);
  csr_build<<<5 * NN,  256, 0, stream>>>(Wout1, H1C, cvals, ccols, cnnz, ROW_WO1);
  csr_build<<<5 * H2C, 256, 0, stream>>>(Wv2,   H2C, cvals, ccols, cnnz, ROW_WV2);
  csr_build<<<5 * NN,  256, 0, stream>>>(Wout2, H2C, cvals, ccols, cnnz, ROW_WO2);
  init_prep<<<dim3(NN / 64, BATCH / 64), 256, 0, stream>>>(x_in, xb, tfT);

  for (int k = 0; k < 10; ++k) {
    const bool g1 = (k % 2 == 0);
    const int j = k / 2;
    const int H = g1 ? H1C : H2C;
    const bf16* BmT = g1 ? B1T : B2T;
    const int* idf = g1 ? idx1f : idx2f;
    const int* idm = g1 ? idx1m : idx2m;
    const int D = g1 ? 6 : 8;
    const int wv_off = g1 ? (ROW_WV1 + j * H1C) : (ROW_WV2 + j * H2C);
    const int wo_off = g1 ? (ROW_WO1 + j * NN)  : (ROW_WO2 + j * NN);
    const float* xcur = (k == 0) ? x_in : xf;

    // chS = x + x @ (S[k]-I):   A = xb (2048x1024), BT = SmIT_k (1024x1024)
    gemm_bt<<<dim3(NN / 128, BATCH / 128), 256, 0, stream>>>(
        xb, SmIT + (size_t)k * NN * NN, chS, chSb, xcur, BATCH, NN, NN);
    // t1T = 2*atanh(clip(cn(tanh(0.5x), idf)))
    cn_kernel<<<dim3(H, BATCH / 256), 256, 0, stream>>>(tfT, idf, D, t1T);
    // zT = BmT @ chS^T : A = BmT (H x 1024), BT = chSb (2048 x 1024) -> (H, 2048)
    gemm_bt<<<dim3(BATCH / 128, H / 128), 256, 0, stream>>>(
        BmT, chSb, zT, nullptr, nullptr, H, BATCH, NN);
    // t2T = tanh(0.5*(zT + Wv @ t1))  (in-place in zT)
    sparse_wv<<<dim3(H, BATCH / 256), 256, 0, stream>>>(zT, t1T, cvals, ccols, cnnz, wv_off);
    // t3T = 2*atanh(clip(cn(t2, idm)))  -> t1T
    cn_kernel<<<dim3(H, BATCH / 256), 256, 0, stream>>>(zT, idm, D, t1T);
    // xpT = Wout @ t3
    sparse_wo<<<dim3(NN, BATCH / 256), 256, 0, stream>>>(t1T, cvals, ccols, cnnz, wo_off, xpT);
    // x_new = chS + xp^T; out[k] = sigmoid(x_new); next-iter xb, tfT
    fuse_out<<<dim3(NN / 64, BATCH / 64), 256, 0, stream>>>(
        xpT, chS, out + (size_t)k * BATCH * NN, xf, xb, tfT);
  }
}

// Round 2
// 3243.652 us; speedup vs baseline: 1.2884x; 1.2884x over previous
//
#include <hip/hip_runtime.h>
#include <hip/hip_bf16.h>
#include <stdint.h>
#include <stddef.h>

using bf16 = __hip_bfloat16;
typedef __attribute__((ext_vector_type(8))) short short8;
typedef __attribute__((ext_vector_type(4))) float f32x4;

constexpr int BATCH = 2048;
constexpr int NN    = 1024;
constexpr int H1C   = 3072;
constexpr int H2C   = 4096;
constexpr int CAP   = 128;   // max nnz per sparse row (Binom(4096,0.01): mean 41, P(>128) ~ 1e-12)

// CSR global row offsets
constexpr int ROW_WV1 = 0;                 // 5*3072 rows, len 3072
constexpr int ROW_WO1 = 5 * H1C;           // 15360: 5*1024 rows, len 3072
constexpr int ROW_WV2 = ROW_WO1 + 5 * NN;  // 20480: 5*4096 rows, len 4096
constexpr int ROW_WO2 = ROW_WV2 + 5 * H2C; // 40960: 5*1024 rows, len 4096
constexpr int ROWS_TOTAL = ROW_WO2 + 5 * NN; // 46080

__device__ __forceinline__ void gload16(const void* g, void* lds_base) {
  __builtin_amdgcn_global_load_lds(
      (const __attribute__((address_space(1))) void*)g,
      (__attribute__((address_space(3))) void*)lds_base, 16, 0, 0);
}

// ---- bf16 MFMA GEMM (m97-structure): C[M,Nd] = A[M,K] @ BT[Nd,K]^T (+add), f32 (+bf16) out
// 128x128 tile, BK=32, 4 waves (each 64x64), global_load_lds staging.
__global__ __launch_bounds__(256, 2) void gemm_bt(
    const bf16* __restrict__ A, const bf16* __restrict__ BT,
    float* __restrict__ C, bf16* __restrict__ Cb, const float* __restrict__ add,
    int M, int Nd, int K)
{
  __shared__ bf16 As[128 * 32];
  __shared__ bf16 Bs[128 * 32];
  const int tid  = threadIdx.x;
  const int lane = tid & 63;
  const int w    = tid >> 6;
  const int bn = blockIdx.x, bm = blockIdx.y;
  const int wm = (w >> 1) * 64, wn = (w & 1) * 64;
  const int l15 = lane & 15;
  const int lk  = (lane >> 4) * 8;   // k elem offset of A/B fragment
  const int ld4 = (lane >> 4) * 4;   // row offset of D fragment
  const int sr  = lane >> 2;         // staging: row within 16-row slot
  const int kc  = (lane & 3) * 8;    // staging: k elem offset

  f32x4 acc[4][4];
#pragma unroll
  for (int i = 0; i < 4; ++i)
#pragma unroll
    for (int j = 0; j < 4; ++j)
#pragma unroll
      for (int e = 0; e < 4; ++e) acc[i][j][e] = 0.f;

  const size_t rA = (size_t)bm * 128;
  const size_t rB = (size_t)bn * 128;

  for (int kt = 0; kt < K; kt += 32) {
#pragma unroll
    for (int c = 0; c < 2; ++c) {
      const int slot = w * 2 + c;             // 8 slots of 16 rows x 32 k (1 KiB)
      const int r = slot * 16 + sr;
      gload16(A  + (rA + r) * (size_t)K + kt + kc, &As[slot * 512]);
      gload16(BT + (rB + r) * (size_t)K + kt + kc, &Bs[slot * 512]);
    }
    __syncthreads();
    short8 af[4], bfr[4];
#pragma unroll
    for (int f = 0; f < 4; ++f) {
      af[f]  = *(const short8*)&As[(wm + f * 16 + l15) * 32 + lk];
      bfr[f] = *(const short8*)&Bs[(wn + f * 16 + l15) * 32 + lk];
    }
#pragma unroll
    for (int i = 0; i < 4; ++i)
#pragma unroll
      for (int j = 0; j < 4; ++j)
        acc[i][j] = __builtin_amdgcn_mfma_f32_16x16x32_bf16(af[i], bfr[j], acc[i][j], 0, 0, 0);
    __syncthreads();
  }

#pragma unroll
  for (int i = 0; i < 4; ++i) {
    const int row0 = bm * 128 + wm + i * 16 + ld4;
#pragma unroll
    for (int j = 0; j < 4; ++j) {
      const int col = bn * 128 + wn + j * 16 + l15;
#pragma unroll
      for (int e = 0; e < 4; ++e) {
        const size_t o = (size_t)(row0 + e) * Nd + col;
        float v = acc[i][j][e];
        if (add) v += add[o];
        C[o] = v;
        if (Cb) Cb[o] = __float2bfloat16(v);
      }
    }
  }
}

// ---- prep: SmIT[k][n][m] = bf16(S[k][m][n] - (m==n))
__global__ __launch_bounds__(256) void prep_smit(const float* __restrict__ S, bf16* __restrict__ out)
{
  __shared__ float ls[64][65];
  const int k = blockIdx.z;
  const int n0 = blockIdx.x * 64, m0 = blockIdx.y * 64;
  const float* Sk = S + (size_t)k * NN * NN;
  bf16* ok = out + (size_t)k * NN * NN;
  const int tc = threadIdx.x & 63, tr = threadIdx.x >> 6;
#pragma unroll
  for (int i = 0; i < 16; ++i) {
    const int r = tr + i * 4;
    ls[r][tc] = Sk[(size_t)(m0 + r) * NN + n0 + tc];
  }
  __syncthreads();
#pragma unroll
  for (int i = 0; i < 16; ++i) {
    const int r = tr + i * 4; // out row n = n0+r, col m = m0+tc
    float v = ls[tc][r] - ((m0 + tc) == (n0 + r) ? 1.f : 0.f);
    ok[(size_t)(n0 + r) * NN + m0 + tc] = __float2bfloat16(v);
  }
}

// ---- prep: out[h][n] = bf16(Bsrc[n][h]);  Bsrc is (NN, H)
__global__ __launch_bounds__(256) void prep_bt(const float* __restrict__ Bsrc, bf16* __restrict__ out, int H)
{
  __shared__ float ls[64][65];
  const int h0 = blockIdx.x * 64, n0 = blockIdx.y * 64;
  const int tc = threadIdx.x & 63, tr = threadIdx.x >> 6;
#pragma unroll
  for (int i = 0; i < 16; ++i) {
    const int r = tr + i * 4;
    ls[r][tc] = Bsrc[(size_t)(n0 + r) * H + h0 + tc];
  }
  __syncthreads();
#pragma unroll
  for (int i = 0; i < 16; ++i) {
    const int r = tr + i * 4; // out row h = h0+r, col n = n0+tc
    out[(size_t)(h0 + r) * NN + n0 + tc] = __float2bfloat16(ls[tc][r]);
  }
}

// ---- CSR build: one block per row, ordered compaction (deterministic)
__global__ __launch_bounds__(256) void csr_build(
    const float* __restrict__ W, int rowlen,
    float* __restrict__ vals, int* __restrict__ cols, int* __restrict__ nnz, int row_off)
{
  const int row = blockIdx.x;
  const float* wr = W + (size_t)row * rowlen;
  const size_t base = (size_t)(row_off + row) * CAP;
  __shared__ int wtot[4];
  __shared__ int cbase;
  if (threadIdx.x == 0) cbase = 0;
  __syncthreads();
  const int lane = threadIdx.x & 63, wv = threadIdx.x >> 6;
  for (int c0 = 0; c0 < rowlen; c0 += 256) {
    const int c = c0 + threadIdx.x;
    const float v = wr[c];
    const bool nz = (v != 0.f);
    const unsigned long long m = __ballot(nz);
    const int rank = __popcll(m & ((1ull << lane) - 1ull));
    if (lane == 0) wtot[wv] = __popcll(m);
    __syncthreads();
    int pre = cbase;
    for (int i = 0; i < wv; ++i) pre += wtot[i];
    if (nz) {
      const int p = pre + rank;
      if (p < CAP) { vals[base + p] = v; cols[base + p] = c; }
    }
    __syncthreads();
    if (threadIdx.x == 0) cbase += wtot[0] + wtot[1] + wtot[2] + wtot[3];
    __syncthreads();
  }
  if (threadIdx.x == 0) nnz[row_off + row] = (cbase < CAP ? cbase : CAP);
}

// ---- cn_update + clip + 2*atanh, 8 batch elems per thread:
//      out[h,b] = log((1+u)/(1-u)), u = clipped prod of nz gathers
__global__ __launch_bounds__(256) void cn_kernel(
    const float* __restrict__ src,   // (rows, BATCH)
    const int* __restrict__ idx, int D,
    float* __restrict__ out)         // (H, BATCH)
{
  const int h = blockIdx.x;
  const int b = threadIdx.x * 8;
  const int* ir = idx + (size_t)h * D;
  float p[8];
  bool any[8];
#pragma unroll
  for (int e = 0; e < 8; ++e) { p[e] = 1.f; any[e] = false; }
  for (int d = 0; d < D; ++d) {
    const float* row = src + (size_t)ir[d] * BATCH + b;
    const f32x4 v0 = *(const f32x4*)row;
    const f32x4 v1 = *(const f32x4*)(row + 4);
#pragma unroll
    for (int e = 0; e < 4; ++e) {
      const bool nz0 = (v0[e] != 0.f);
      any[e] |= nz0;
      p[e] *= nz0 ? v0[e] : 1.f;
      const bool nz1 = (v1[e] != 0.f);
      any[e + 4] |= nz1;
      p[e + 4] *= nz1 ? v1[e] : 1.f;
    }
  }
  f32x4 o0, o1;
#pragma unroll
  for (int e = 0; e < 8; ++e) {
    float u = any[e] ? p[e] : 0.f;
    u = fminf(fmaxf(u, -0.999999f), 0.999999f);
    const float r = logf((1.f + u) / (1.f - u));
    if (e < 4) o0[e] = r; else o1[e - 4] = r;
  }
  float* orow = out + (size_t)h * BATCH + b;
  *(f32x4*)orow = o0;
  *(f32x4*)(orow + 4) = o1;
}

// ---- sparse Wv apply + tanh (in-place on z), 8 batch elems per thread
__global__ __launch_bounds__(256) void sparse_wv(
    float* __restrict__ zio, const float* __restrict__ t1,
    const float* __restrict__ vals, const int* __restrict__ cols, const int* __restrict__ nnz,
    int rowoff)
{
  const int h = blockIdx.x;
  const int b = threadIdx.x * 8;
  const int rg = rowoff + h;
  const float* vr = vals + (size_t)rg * CAP;
  const int*   cr = cols + (size_t)rg * CAP;
  const int n = nnz[rg];
  float* zrow = zio + (size_t)h * BATCH + b;
  f32x4 a0 = *(const f32x4*)zrow;
  f32x4 a1 = *(const f32x4*)(zrow + 4);
  for (int j = 0; j < n; ++j) {
    const float v = vr[j];
    const float* trow = t1 + (size_t)cr[j] * BATCH + b;
    const f32x4 t0 = *(const f32x4*)trow;
    const f32x4 t1v = *(const f32x4*)(trow + 4);
#pragma unroll
    for (int e = 0; e < 4; ++e) {
      a0[e] += v * t0[e];
      a1[e] += v * t1v[e];
    }
  }
#pragma unroll
  for (int e = 0; e < 4; ++e) {
    a0[e] = tanhf(0.5f * a0[e]);
    a1[e] = tanhf(0.5f * a1[e]);
  }
  *(f32x4*)zrow = a0;
  *(f32x4*)(zrow + 4) = a1;
}

// ---- sparse Wout apply, 8 batch elems per thread: xp[n,b] = sum val*t3[col,b]
__global__ __launch_bounds__(256) void sparse_wo(
    const float* __restrict__ t3,
    const float* __restrict__ vals, const int* __restrict__ cols, const int* __restrict__ nnz,
    int rowoff, float* __restrict__ xp)
{
  const int nrow = blockIdx.x;
  const int b = threadIdx.x * 8;
  const int rg = rowoff + nrow;
  const float* vr = vals + (size_t)rg * CAP;
  const int*   cr = cols + (size_t)rg * CAP;
  const int cnt = nnz[rg];
  f32x4 a0 = {0.f, 0.f, 0.f, 0.f};
  f32x4 a1 = {0.f, 0.f, 0.f, 0.f};
  for (int j = 0; j < cnt; ++j) {
    const float v = vr[j];
    const float* trow = t3 + (size_t)cr[j] * BATCH + b;
    const f32x4 t0 = *(const f32x4*)trow;
    const f32x4 t1v = *(const f32x4*)(trow + 4);
#pragma unroll
    for (int e = 0; e < 4; ++e) {
      a0[e] += v * t0[e];
      a1[e] += v * t1v[e];
    }
  }
  float* orow = xp + (size_t)nrow * BATCH + b;
  *(f32x4*)orow = a0;
  *(f32x4*)(orow + 4) = a1;
}

// ---- fused epilogue: x_new = chS + xp^T; write sigmoid->out, x f32, x bf16 (B,N) and tanh(0.5x)->tfT (N,B)
__global__ __launch_bounds__(256) void fuse_out(
    const float* __restrict__ xpT,  // (NN, BATCH)
    const float* __restrict__ chS,  // (BATCH, NN)
    float* __restrict__ dout,       // (BATCH, NN)
    float* __restrict__ xf,         // (BATCH, NN)
    bf16* __restrict__ xb,          // (BATCH, NN)
    float* __restrict__ tfT)        // (NN, BATCH)
{
  __shared__ float lc[64][65];  // chS tile [b][n]
  __shared__ float lx[64][65];  // xpT tile [n][b]
  const int n0 = blockIdx.x * 64, b0 = blockIdx.y * 64;
  const int tc = threadIdx.x & 63, tr = threadIdx.x >> 6;
#pragma unroll
  for (int i = 0; i < 16; ++i) {
    const int r = tr + i * 4;
    lc[r][tc] = chS[(size_t)(b0 + r) * NN + n0 + tc];
    lx[r][tc] = xpT[(size_t)(n0 + r) * BATCH + b0 + tc];
  }
  __syncthreads();
#pragma unroll
  for (int i = 0; i < 16; ++i) {      // (B,N) orientation: r=local b, tc=local n
    const int r = tr + i * 4;
    const float v = lc[r][tc] + lx[tc][r];
    const size_t o = (size_t)(b0 + r) * NN + n0 + tc;
    dout[o] = 1.f / (1.f + expf(-v));
    xf[o] = v;
    xb[o] = __float2bfloat16(v);
  }
#pragma unroll
  for (int i = 0; i < 16; ++i) {      // (N,B) orientation: r=local n, tc=local b
    const int r = tr + i * 4;
    const float v = lc[tc][r] + lx[r][tc];
    tfT[(size_t)(n0 + r) * BATCH + b0 + tc] = tanhf(0.5f * v);
  }
}

// ---- initial prep (k=0): from x (B,N) make xb (B,N) and tfT (N,B)
__global__ __launch_bounds__(256) void init_prep(
    const float* __restrict__ x, bf16* __restrict__ xb, float* __restrict__ tfT)
{
  __shared__ float ls[64][65];
  const int n0 = blockIdx.x * 64, b0 = blockIdx.y * 64;
  const int tc = threadIdx.x & 63, tr = threadIdx.x >> 6;
#pragma unroll
  for (int i = 0; i < 16; ++i) {
    const int r = tr + i * 4;
    const size_t o = (size_t)(b0 + r) * NN + n0 + tc;
    const float v = x[o];
    ls[r][tc] = v;
    xb[o] = __float2bfloat16(v);
  }
  __syncthreads();
#pragma unroll
  for (int i = 0; i < 16; ++i) {
    const int r = tr + i * 4; // r = local n, tc = local b
    tfT[(size_t)(n0 + r) * BATCH + b0 + tc] = tanhf(0.5f * ls[tc][r]);
  }
}

extern "C" void kernel_launch(void* const* d_in, const int* in_sizes, int n_in,
                              void* d_out, int out_size, void* d_ws, size_t ws_size,
                              hipStream_t stream)
{
  const float* x_in  = (const float*)d_in[0];
  const float* S     = (const float*)d_in[1];
  const float* B1    = (const float*)d_in[2];
  const float* B2    = (const float*)d_in[3];
  const float* Wv1   = (const float*)d_in[4];
  const float* Wout1 = (const float*)d_in[5];
  const float* Wv2   = (const float*)d_in[6];
  const float* Wout2 = (const float*)d_in[7];
  const int* idx1f   = (const int*)d_in[8];
  const int* idx1m   = (const int*)d_in[9];
  const int* idx2f   = (const int*)d_in[10];
  const int* idx2m   = (const int*)d_in[11];
  float* out = (float*)d_out;

  uint8_t* p = (uint8_t*)d_ws;
  auto alloc = [&](size_t bytes) -> void* {
    void* r = p;
    p += (bytes + 255) & ~(size_t)255;
    return r;
  };
  bf16*  SmIT = (bf16*)alloc((size_t)10 * NN * NN * sizeof(bf16));
  bf16*  B1T  = (bf16*)alloc((size_t)H1C * NN * sizeof(bf16));
  bf16*  B2T  = (bf16*)alloc((size_t)H2C * NN * sizeof(bf16));
  float* cvals = (float*)alloc((size_t)ROWS_TOTAL * CAP * sizeof(float));
  int*   ccols = (int*)alloc((size_t)ROWS_TOTAL * CAP * sizeof(int));
  int*   cnnz  = (int*)alloc((size_t)ROWS_TOTAL * sizeof(int));
  float* xf   = (float*)alloc((size_t)BATCH * NN * sizeof(float));
  bf16*  xb   = (bf16*)alloc((size_t)BATCH * NN * sizeof(bf16));
  float* tfT  = (float*)alloc((size_t)NN * BATCH * sizeof(float));
  float* chS  = (float*)alloc((size_t)BATCH * NN * sizeof(float));
  bf16*  chSb = (bf16*)alloc((size_t)BATCH * NN * sizeof(bf16));
  float* t1T  = (float*)alloc((size_t)H2C * BATCH * sizeof(float)); // also t3T
  float* zT   = (float*)alloc((size_t)H2C * BATCH * sizeof(float)); // also t2T (in-place)
  float* xpT  = (float*)alloc((size_t)NN * BATCH * sizeof(float));
  (void)ws_size; (void)in_sizes; (void)n_in; (void)out_size;

  // --- per-call prep
  prep_smit<<<dim3(NN / 64, NN / 64, 10), 256, 0, stream>>>(S, SmIT);
  prep_bt<<<dim3(H1C / 64, NN / 64), 256, 0, stream>>>(B1, B1T, H1C);
  prep_bt<<<dim3(H2C / 64, NN / 64), 256, 0, stream>>>(B2, B2T, H2C);
  csr_build<<<5 * H1C, 256, 0, stream>>>(Wv1,   H1C, cvals, ccols, cnnz, ROW_WV1);
  csr_build<<<5 * NN,  256, 0, stream>>>(Wout1, H1C, cvals, ccols, cnnz, ROW_WO1);
  csr_build<<<5 * H2C, 256, 0, stream>>>(Wv2,   H2C, cvals, ccols, cnnz, ROW_WV2);
  csr_build<<<5 * NN,  256, 0, stream>>>(Wout2, H2C, cvals, ccols, cnnz, ROW_WO2);
  init_prep<<<dim3(NN / 64, BATCH / 64), 256, 0, stream>>>(x_in, xb, tfT);

  for (int k = 0; k < 10; ++k) {
    const bool g1 = (k % 2 == 0);
    const int j = k / 2;
    const int H = g1 ? H1C : H2C;
    const bf16* BmT = g1 ? B1T : B2T;
    const int* idf = g1 ? idx1f : idx2f;
    const int* idm = g1 ? idx1m : idx2m;
    const int D = g1 ? 6 : 8;
    const int wv_off = g1 ? (ROW_WV1 + j * H1C) : (ROW_WV2 + j * H2C);
    const int wo_off = g1 ? (ROW_WO1 + j * NN)  : (ROW_WO2 + j * NN);
    const float* xcur = (k == 0) ? x_in : xf;

    // chS = x + x @ (S[k]-I):   A = xb (2048x1024), BT = SmIT_k (1024x1024)
    gemm_bt<<<dim3(NN / 128, BATCH / 128), 256, 0, stream>>>(
        xb, SmIT + (size_t)k * NN * NN, chS, chSb, xcur, BATCH, NN, NN);
    // t1T = 2*atanh(clip(cn(tanh(0.5x), idf)))
    cn_kernel<<<dim3(H, 1), 256, 0, stream>>>(tfT, idf, D, t1T);
    // zT = BmT @ chS^T : A = BmT (H x 1024), BT = chSb (2048 x 1024) -> (H, 2048)
    gemm_bt<<<dim3(BATCH / 128, H / 128), 256, 0, stream>>>(
        BmT, chSb, zT, nullptr, nullptr, H, BATCH, NN);
    // t2T = tanh(0.5*(zT + Wv @ t1))  (in-place in zT)
    sparse_wv<<<dim3(H, 1), 256, 0, stream>>>(zT, t1T, cvals, ccols, cnnz, wv_off);
    // t3T = 2*atanh(clip(cn(t2, idm)))  -> t1T
    cn_kernel<<<dim3(H, 1), 256, 0, stream>>>(zT, idm, D, t1T);
    // xpT = Wout @ t3
    sparse_wo<<<dim3(NN, 1), 256, 0, stream>>>(t1T, cvals, ccols, cnnz, wo_off, xpT);
    // x_new = chS + xp^T; out[k] = sigmoid(x_new); next-iter xb, tfT
    fuse_out<<<dim3(NN / 64, BATCH / 64), 256, 0, stream>>>(
        xpT, chS, out + (size_t)k * BATCH * NN, xf, xb, tfT);
  }
}

// Round 3
// 2424.942 us; speedup vs baseline: 1.7234x; 1.3376x over previous
//
#include <hip/hip_runtime.h>
#include <hip/hip_bf16.h>
#include <stdint.h>
#include <stddef.h>

using bf16 = __hip_bfloat16;
typedef __attribute__((ext_vector_type(8))) short short8;
typedef __attribute__((ext_vector_type(4))) float f32x4;

constexpr int BATCH = 2048;
constexpr int NN    = 1024;
constexpr int H1C   = 3072;
constexpr int H2C   = 4096;
constexpr int CAP   = 128;   // max nnz per sparse row (Binom(4096,0.01): mean 41, P(>128) ~ 1e-12)

// CSR global row offsets
constexpr int ROW_WV1 = 0;                 // 5*3072 rows, len 3072
constexpr int ROW_WO1 = 5 * H1C;           // 15360: 5*1024 rows, len 3072
constexpr int ROW_WV2 = ROW_WO1 + 5 * NN;  // 20480: 5*4096 rows, len 4096
constexpr int ROW_WO2 = ROW_WV2 + 5 * H2C; // 40960: 5*1024 rows, len 4096
constexpr int ROWS_TOTAL = ROW_WO2 + 5 * NN; // 46080

__device__ __forceinline__ unsigned short f2bf(float f) {
  unsigned u = __float_as_uint(f);
  unsigned r = 0x7FFFu + ((u >> 16) & 1u);
  return (unsigned short)((u + r) >> 16);
}
__device__ __forceinline__ float bf2f(short s) {
  return __uint_as_float(((unsigned)(unsigned short)s) << 16);
}

__device__ __forceinline__ void gload16(const void* g, void* lds_base) {
  __builtin_amdgcn_global_load_lds(
      (const __attribute__((address_space(1))) void*)g,
      (__attribute__((address_space(3))) void*)lds_base, 16, 0, 0);
}

// ---- bf16 MFMA GEMM (m97-structure): C[M,Nd] = A[M,K] @ BT[Nd,K]^T (+add), f32 (+bf16) out
// 128x128 tile, BK=32, 4 waves (each 64x64), global_load_lds staging.
__global__ __launch_bounds__(256, 2) void gemm_bt(
    const bf16* __restrict__ A, const bf16* __restrict__ BT,
    float* __restrict__ C, bf16* __restrict__ Cb, const float* __restrict__ add,
    int M, int Nd, int K)
{
  __shared__ bf16 As[128 * 32];
  __shared__ bf16 Bs[128 * 32];
  const int tid  = threadIdx.x;
  const int lane = tid & 63;
  const int w    = tid >> 6;
  const int bn = blockIdx.x, bm = blockIdx.y;
  const int wm = (w >> 1) * 64, wn = (w & 1) * 64;
  const int l15 = lane & 15;
  const int lk  = (lane >> 4) * 8;   // k elem offset of A/B fragment
  const int ld4 = (lane >> 4) * 4;   // row offset of D fragment
  const int sr  = lane >> 2;         // staging: row within 16-row slot
  const int kc  = (lane & 3) * 8;    // staging: k elem offset

  f32x4 acc[4][4];
#pragma unroll
  for (int i = 0; i < 4; ++i)
#pragma unroll
    for (int j = 0; j < 4; ++j)
#pragma unroll
      for (int e = 0; e < 4; ++e) acc[i][j][e] = 0.f;

  const size_t rA = (size_t)bm * 128;
  const size_t rB = (size_t)bn * 128;

  for (int kt = 0; kt < K; kt += 32) {
#pragma unroll
    for (int c = 0; c < 2; ++c) {
      const int slot = w * 2 + c;             // 8 slots of 16 rows x 32 k (1 KiB)
      const int r = slot * 16 + sr;
      gload16(A  + (rA + r) * (size_t)K + kt + kc, &As[slot * 512]);
      gload16(BT + (rB + r) * (size_t)K + kt + kc, &Bs[slot * 512]);
    }
    __syncthreads();
    short8 af[4], bfr[4];
#pragma unroll
    for (int f = 0; f < 4; ++f) {
      af[f]  = *(const short8*)&As[(wm + f * 16 + l15) * 32 + lk];
      bfr[f] = *(const short8*)&Bs[(wn + f * 16 + l15) * 32 + lk];
    }
#pragma unroll
    for (int i = 0; i < 4; ++i)
#pragma unroll
      for (int j = 0; j < 4; ++j)
        acc[i][j] = __builtin_amdgcn_mfma_f32_16x16x32_bf16(af[i], bfr[j], acc[i][j], 0, 0, 0);
    __syncthreads();
  }

#pragma unroll
  for (int i = 0; i < 4; ++i) {
    const int row0 = bm * 128 + wm + i * 16 + ld4;
#pragma unroll
    for (int j = 0; j < 4; ++j) {
      const int col = bn * 128 + wn + j * 16 + l15;
#pragma unroll
      for (int e = 0; e < 4; ++e) {
        const size_t o = (size_t)(row0 + e) * Nd + col;
        float v = acc[i][j][e];
        if (add) v += add[o];
        C[o] = v;
        if (Cb) Cb[o] = __float2bfloat16(v);
      }
    }
  }
}

// ---- prep: SmIT[k][n][m] = bf16(S[k][m][n] - (m==n))
__global__ __launch_bounds__(256) void prep_smit(const float* __restrict__ S, bf16* __restrict__ out)
{
  __shared__ float ls[64][65];
  const int k = blockIdx.z;
  const int n0 = blockIdx.x * 64, m0 = blockIdx.y * 64;
  const float* Sk = S + (size_t)k * NN * NN;
  bf16* ok = out + (size_t)k * NN * NN;
  const int tc = threadIdx.x & 63, tr = threadIdx.x >> 6;
#pragma unroll
  for (int i = 0; i < 16; ++i) {
    const int r = tr + i * 4;
    ls[r][tc] = Sk[(size_t)(m0 + r) * NN + n0 + tc];
  }
  __syncthreads();
#pragma unroll
  for (int i = 0; i < 16; ++i) {
    const int r = tr + i * 4; // out row n = n0+r, col m = m0+tc
    float v = ls[tc][r] - ((m0 + tc) == (n0 + r) ? 1.f : 0.f);
    ok[(size_t)(n0 + r) * NN + m0 + tc] = __float2bfloat16(v);
  }
}

// ---- prep: out[h][n] = bf16(Bsrc[n][h]);  Bsrc is (NN, H)
__global__ __launch_bounds__(256) void prep_bt(const float* __restrict__ Bsrc, bf16* __restrict__ out, int H)
{
  __shared__ float ls[64][65];
  const int h0 = blockIdx.x * 64, n0 = blockIdx.y * 64;
  const int tc = threadIdx.x & 63, tr = threadIdx.x >> 6;
#pragma unroll
  for (int i = 0; i < 16; ++i) {
    const int r = tr + i * 4;
    ls[r][tc] = Bsrc[(size_t)(n0 + r) * H + h0 + tc];
  }
  __syncthreads();
#pragma unroll
  for (int i = 0; i < 16; ++i) {
    const int r = tr + i * 4; // out row h = h0+r, col n = n0+tc
    out[(size_t)(h0 + r) * NN + n0 + tc] = __float2bfloat16(ls[tc][r]);
  }
}

// ---- CSR build: one block per row, ordered compaction (deterministic)
__global__ __launch_bounds__(256) void csr_build(
    const float* __restrict__ W, int rowlen,
    float* __restrict__ vals, int* __restrict__ cols, int* __restrict__ nnz, int row_off)
{
  const int row = blockIdx.x;
  const float* wr = W + (size_t)row * rowlen;
  const size_t base = (size_t)(row_off + row) * CAP;
  __shared__ int wtot[4];
  __shared__ int cbase;
  if (threadIdx.x == 0) cbase = 0;
  __syncthreads();
  const int lane = threadIdx.x & 63, wv = threadIdx.x >> 6;
  for (int c0 = 0; c0 < rowlen; c0 += 256) {
    const int c = c0 + threadIdx.x;
    const float v = wr[c];
    const bool nz = (v != 0.f);
    const unsigned long long m = __ballot(nz);
    const int rank = __popcll(m & ((1ull << lane) - 1ull));
    if (lane == 0) wtot[wv] = __popcll(m);
    __syncthreads();
    int pre = cbase;
    for (int i = 0; i < wv; ++i) pre += wtot[i];
    if (nz) {
      const int p = pre + rank;
      if (p < CAP) { vals[base + p] = v; cols[base + p] = c; }
    }
    __syncthreads();
    if (threadIdx.x == 0) cbase += wtot[0] + wtot[1] + wtot[2] + wtot[3];
    __syncthreads();
  }
  if (threadIdx.x == 0) nnz[row_off + row] = (cbase < CAP ? cbase : CAP);
}

// ---- cn_update + clip + 2*atanh, 8 batch elems per thread:
//      out[h,b] = bf16( log((1+u)/(1-u)) ), u = clipped prod of nz gathers (f32 source)
__global__ __launch_bounds__(256) void cn_kernel(
    const float* __restrict__ src,   // (rows, BATCH) f32
    const int* __restrict__ idx, int D,
    unsigned short* __restrict__ out) // (H, BATCH) bf16
{
  const int h = blockIdx.x;
  const int b = threadIdx.x * 8;
  const int* ir = idx + (size_t)h * D;
  float p[8];
  bool any[8];
#pragma unroll
  for (int e = 0; e < 8; ++e) { p[e] = 1.f; any[e] = false; }
  for (int d = 0; d < D; ++d) {
    const float* row = src + (size_t)ir[d] * BATCH + b;
    const f32x4 v0 = *(const f32x4*)row;
    const f32x4 v1 = *(const f32x4*)(row + 4);
#pragma unroll
    for (int e = 0; e < 4; ++e) {
      const bool nz0 = (v0[e] != 0.f);
      any[e] |= nz0;
      p[e] *= nz0 ? v0[e] : 1.f;
      const bool nz1 = (v1[e] != 0.f);
      any[e + 4] |= nz1;
      p[e + 4] *= nz1 ? v1[e] : 1.f;
    }
  }
  short8 ov;
#pragma unroll
  for (int e = 0; e < 8; ++e) {
    float u = any[e] ? p[e] : 0.f;
    u = fminf(fmaxf(u, -0.999999f), 0.999999f);
    const float r = logf((1.f + u) / (1.f - u));
    ov[e] = (short)f2bf(r);
  }
  *(short8*)(out + (size_t)h * BATCH + b) = ov;
}

// ---- sparse Wv apply + tanh (in-place on z), 8 batch elems per thread; t1 is bf16
__global__ __launch_bounds__(256) void sparse_wv(
    float* __restrict__ zio, const unsigned short* __restrict__ t1,
    const float* __restrict__ vals, const int* __restrict__ cols, const int* __restrict__ nnz,
    int rowoff)
{
  const int h = blockIdx.x;
  const int b = threadIdx.x * 8;
  const int rg = rowoff + h;
  const float* vr = vals + (size_t)rg * CAP;
  const int*   cr = cols + (size_t)rg * CAP;
  const int n = nnz[rg];
  float* zrow = zio + (size_t)h * BATCH + b;
  f32x4 a0 = *(const f32x4*)zrow;
  f32x4 a1 = *(const f32x4*)(zrow + 4);
  for (int j = 0; j < n; ++j) {
    const float v = vr[j];
    const short8 t = *(const short8*)(t1 + (size_t)cr[j] * BATCH + b);
#pragma unroll
    for (int e = 0; e < 4; ++e) {
      a0[e] += v * bf2f(t[e]);
      a1[e] += v * bf2f(t[e + 4]);
    }
  }
#pragma unroll
  for (int e = 0; e < 4; ++e) {
    a0[e] = tanhf(0.5f * a0[e]);
    a1[e] = tanhf(0.5f * a1[e]);
  }
  *(f32x4*)zrow = a0;
  *(f32x4*)(zrow + 4) = a1;
}

// ---- sparse Wout apply, 8 batch elems per thread: xp[n,b] = sum val*t3[col,b]; t3 is bf16
__global__ __launch_bounds__(256) void sparse_wo(
    const unsigned short* __restrict__ t3,
    const float* __restrict__ vals, const int* __restrict__ cols, const int* __restrict__ nnz,
    int rowoff, float* __restrict__ xp)
{
  const int nrow = blockIdx.x;
  const int b = threadIdx.x * 8;
  const int rg = rowoff + nrow;
  const float* vr = vals + (size_t)rg * CAP;
  const int*   cr = cols + (size_t)rg * CAP;
  const int cnt = nnz[rg];
  f32x4 a0 = {0.f, 0.f, 0.f, 0.f};
  f32x4 a1 = {0.f, 0.f, 0.f, 0.f};
  for (int j = 0; j < cnt; ++j) {
    const float v = vr[j];
    const short8 t = *(const short8*)(t3 + (size_t)cr[j] * BATCH + b);
#pragma unroll
    for (int e = 0; e < 4; ++e) {
      a0[e] += v * bf2f(t[e]);
      a1[e] += v * bf2f(t[e + 4]);
    }
  }
  float* orow = xp + (size_t)nrow * BATCH + b;
  *(f32x4*)orow = a0;
  *(f32x4*)(orow + 4) = a1;
}

// ---- fused epilogue: x_new = chS + xp^T; write sigmoid->out, x f32, x bf16 (B,N) and tanh(0.5x)->tfT (N,B)
__global__ __launch_bounds__(256) void fuse_out(
    const float* __restrict__ xpT,  // (NN, BATCH)
    const float* __restrict__ chS,  // (BATCH, NN)
    float* __restrict__ dout,       // (BATCH, NN)
    float* __restrict__ xf,         // (BATCH, NN)
    bf16* __restrict__ xb,          // (BATCH, NN)
    float* __restrict__ tfT)        // (NN, BATCH)
{
  __shared__ float lc[64][65];  // chS tile [b][n]
  __shared__ float lx[64][65];  // xpT tile [n][b]
  const int n0 = blockIdx.x * 64, b0 = blockIdx.y * 64;
  const int tc = threadIdx.x & 63, tr = threadIdx.x >> 6;
#pragma unroll
  for (int i = 0; i < 16; ++i) {
    const int r = tr + i * 4;
    lc[r][tc] = chS[(size_t)(b0 + r) * NN + n0 + tc];
    lx[r][tc] = xpT[(size_t)(n0 + r) * BATCH + b0 + tc];
  }
  __syncthreads();
#pragma unroll
  for (int i = 0; i < 16; ++i) {      // (B,N) orientation: r=local b, tc=local n
    const int r = tr + i * 4;
    const float v = lc[r][tc] + lx[tc][r];
    const size_t o = (size_t)(b0 + r) * NN + n0 + tc;
    dout[o] = 1.f / (1.f + expf(-v));
    xf[o] = v;
    xb[o] = __float2bfloat16(v);
  }
#pragma unroll
  for (int i = 0; i < 16; ++i) {      // (N,B) orientation: r=local n, tc=local b
    const int r = tr + i * 4;
    const float v = lc[tc][r] + lx[r][tc];
    tfT[(size_t)(n0 + r) * BATCH + b0 + tc] = tanhf(0.5f * v);
  }
}

// ---- initial prep (k=0): from x (B,N) make xb (B,N) and tfT (N,B)
__global__ __launch_bounds__(256) void init_prep(
    const float* __restrict__ x, bf16* __restrict__ xb, float* __restrict__ tfT)
{
  __shared__ float ls[64][65];
  const int n0 = blockIdx.x * 64, b0 = blockIdx.y * 64;
  const int tc = threadIdx.x & 63, tr = threadIdx.x >> 6;
#pragma unroll
  for (int i = 0; i < 16; ++i) {
    const int r = tr + i * 4;
    const size_t o = (size_t)(b0 + r) * NN + n0 + tc;
    const float v = x[o];
    ls[r][tc] = v;
    xb[o] = __float2bfloat16(v);
  }
  __syncthreads();
#pragma unroll
  for (int i = 0; i < 16; ++i) {
    const int r = tr + i * 4; // r = local n, tc = local b
    tfT[(size_t)(n0 + r) * BATCH + b0 + tc] = tanhf(0.5f * ls[tc][r]);
  }
}

extern "C" void kernel_launch(void* const* d_in, const int* in_sizes, int n_in,
                              void* d_out, int out_size, void* d_ws, size_t ws_size,
                              hipStream_t stream)
{
  const float* x_in  = (const float*)d_in[0];
  const float* S     = (const float*)d_in[1];
  const float* B1    = (const float*)d_in[2];
  const float* B2    = (const float*)d_in[3];
  const float* Wv1   = (const float*)d_in[4];
  const float* Wout1 = (const float*)d_in[5];
  const float* Wv2   = (const float*)d_in[6];
  const float* Wout2 = (const float*)d_in[7];
  const int* idx1f   = (const int*)d_in[8];
  const int* idx1m   = (const int*)d_in[9];
  const int* idx2f   = (const int*)d_in[10];
  const int* idx2m   = (const int*)d_in[11];
  float* out = (float*)d_out;

  uint8_t* p = (uint8_t*)d_ws;
  auto alloc = [&](size_t bytes) -> void* {
    void* r = p;
    p += (bytes + 255) & ~(size_t)255;
    return r;
  };
  bf16*  SmIT = (bf16*)alloc((size_t)10 * NN * NN * sizeof(bf16));
  bf16*  B1T  = (bf16*)alloc((size_t)H1C * NN * sizeof(bf16));
  bf16*  B2T  = (bf16*)alloc((size_t)H2C * NN * sizeof(bf16));
  float* cvals = (float*)alloc((size_t)ROWS_TOTAL * CAP * sizeof(float));
  int*   ccols = (int*)alloc((size_t)ROWS_TOTAL * CAP * sizeof(int));
  int*   cnnz  = (int*)alloc((size_t)ROWS_TOTAL * sizeof(int));
  float* xf   = (float*)alloc((size_t)BATCH * NN * sizeof(float));
  bf16*  xb   = (bf16*)alloc((size_t)BATCH * NN * sizeof(bf16));
  float* tfT  = (float*)alloc((size_t)NN * BATCH * sizeof(float));
  float* chS  = (float*)alloc((size_t)BATCH * NN * sizeof(float));
  bf16*  chSb = (bf16*)alloc((size_t)BATCH * NN * sizeof(bf16));
  unsigned short* t1T = (unsigned short*)alloc((size_t)H2C * BATCH * sizeof(unsigned short)); // bf16 t1/t3
  float* zT   = (float*)alloc((size_t)H2C * BATCH * sizeof(float)); // also t2T (in-place)
  float* xpT  = (float*)alloc((size_t)NN * BATCH * sizeof(float));
  (void)ws_size; (void)in_sizes; (void)n_in; (void)out_size;

  // --- per-call prep
  prep_smit<<<dim3(NN / 64, NN / 64, 10), 256, 0, stream>>>(S, SmIT);
  prep_bt<<<dim3(H1C / 64, NN / 64), 256, 0, stream>>>(B1, B1T, H1C);
  prep_bt<<<dim3(H2C / 64, NN / 64), 256, 0, stream>>>(B2, B2T, H2C);
  csr_build<<<5 * H1C, 256, 0, stream>>>(Wv1,   H1C, cvals, ccols, cnnz, ROW_WV1);
  csr_build<<<5 * NN,  256, 0, stream>>>(Wout1, H1C, cvals, ccols, cnnz, ROW_WO1);
  csr_build<<<5 * H2C, 256, 0, stream>>>(Wv2,   H2C, cvals, ccols, cnnz, ROW_WV2);
  csr_build<<<5 * NN,  256, 0, stream>>>(Wout2, H2C, cvals, ccols, cnnz, ROW_WO2);
  init_prep<<<dim3(NN / 64, BATCH / 64), 256, 0, stream>>>(x_in, xb, tfT);

  for (int k = 0; k < 10; ++k) {
    const bool g1 = (k % 2 == 0);
    const int j = k / 2;
    const int H = g1 ? H1C : H2C;
    const bf16* BmT = g1 ? B1T : B2T;
    const int* idf = g1 ? idx1f : idx2f;
    const int* idm = g1 ? idx1m : idx2m;
    const int D = g1 ? 6 : 8;
    const int wv_off = g1 ? (ROW_WV1 + j * H1C) : (ROW_WV2 + j * H2C);
    const int wo_off = g1 ? (ROW_WO1 + j * NN)  : (ROW_WO2 + j * NN);
    const float* xcur = (k == 0) ? x_in : xf;

    // chS = x + x @ (S[k]-I):   A = xb (2048x1024), BT = SmIT_k (1024x1024)
    gemm_bt<<<dim3(NN / 128, BATCH / 128), 256, 0, stream>>>(
        xb, SmIT + (size_t)k * NN * NN, chS, chSb, xcur, BATCH, NN, NN);
    // t1T = bf16( 2*atanh(clip(cn(tanh(0.5x), idf))) )
    cn_kernel<<<dim3(H, 1), 256, 0, stream>>>(tfT, idf, D, t1T);
    // zT = BmT @ chS^T : A = BmT (H x 1024), BT = chSb (2048 x 1024) -> (H, 2048)
    gemm_bt<<<dim3(BATCH / 128, H / 128), 256, 0, stream>>>(
        BmT, chSb, zT, nullptr, nullptr, H, BATCH, NN);
    // t2T = tanh(0.5*(zT + Wv @ t1))  (in-place in zT, f32)
    sparse_wv<<<dim3(H, 1), 256, 0, stream>>>(zT, t1T, cvals, ccols, cnnz, wv_off);
    // t3T = bf16( 2*atanh(clip(cn(t2, idm))) )  -> t1T
    cn_kernel<<<dim3(H, 1), 256, 0, stream>>>(zT, idm, D, t1T);
    // xpT = Wout @ t3
    sparse_wo<<<dim3(NN, 1), 256, 0, stream>>>(t1T, cvals, ccols, cnnz, wo_off, xpT);
    // x_new = chS + xp^T; out[k] = sigmoid(x_new); next-iter xb, tfT
    fuse_out<<<dim3(NN / 64, BATCH / 64), 256, 0, stream>>>(
        xpT, chS, out + (size_t)k * BATCH * NN, xf, xb, tfT);
  }
}